// Round 10
// baseline (1988.030 us; speedup 1.0000x reference)
//
#include <hip/hip_runtime.h>
#include <hip/hip_bf16.h>

#define NIMG 4
#define GRID 1024

typedef __attribute__((ext_vector_type(8))) _Float16 half8v;
typedef __attribute__((ext_vector_type(4))) float float4v;

__device__ __forceinline__ float sigm(float x){ return 1.f/(1.f+__expf(-x)); }
__device__ __forceinline__ float silu(float x){ return x/(1.f+__expf(-x)); }
__device__ __forceinline__ float lrelu(float x){ return fmaxf(x, 0.01f*x); }

template<int CTRL>
__device__ __forceinline__ float dpp_radd(float v){
  int s = __builtin_amdgcn_update_dpp(0, __builtin_bit_cast(int, v), CTRL, 0xF, 0xF, true);
  return v + __builtin_bit_cast(float, s);
}
__device__ __forceinline__ float row16_reduce(float v){
  v = dpp_radd<0x128>(v);  // row_ror:8
  v = dpp_radd<0x124>(v);  // row_ror:4
  v = dpp_radd<0x122>(v);  // row_ror:2
  v = dpp_radd<0x121>(v);  // row_ror:1
  return v;
}

struct Params {
  const float *tf, *Wtok, *btok;
  const float *ms1, *ms0;
  const float *la, *Wa, *ba;
  const float *Wint;
  const float *Wc0, *bc0, *Wc1, *bc1;
  const float *Wp, *bp, *Wcat, *bcat, *Wgate, *bgate;
  const float *lg, *Wg, *bg, *W1, *b1, *W2, *b2;
  const float *bint, *Wpe, *bpe, *Wpg, *bpg;
  const int *batch;
  int *bar;
  float *sumsilu, *S1, *S0, *atom_e, *pf, *out;
  unsigned short *atoms_h, *Wt, *tok_h;
};

// generational grid barrier; all GRID blocks must be co-resident.
__device__ __forceinline__ void gridbar(int* bar){
  __threadfence();                 // release my writes (agent scope)
  __syncthreads();
  if(threadIdx.x==0){
    int g = __hip_atomic_load(&bar[1], __ATOMIC_RELAXED, __HIP_MEMORY_SCOPE_AGENT);
    int old = __hip_atomic_fetch_add(&bar[0], 1, __ATOMIC_ACQ_REL, __HIP_MEMORY_SCOPE_AGENT);
    if(old == GRID-1){
      __hip_atomic_store(&bar[0], 0, __ATOMIC_RELAXED, __HIP_MEMORY_SCOPE_AGENT);
      __hip_atomic_fetch_add(&bar[1], 1, __ATOMIC_RELEASE, __HIP_MEMORY_SCOPE_AGENT);
    } else {
      while(__hip_atomic_load(&bar[1], __ATOMIC_ACQUIRE, __HIP_MEMORY_SCOPE_AGENT) == g)
        __builtin_amdgcn_s_sleep(8);
    }
  }
  __syncthreads();
  __threadfence();                 // acquire: see others' writes
}

template<int DIM, int ODIM>
__device__ void wsum_body(const float* __restrict__ x, float* __restrict__ S,
                          int vb, float* sh){
  const float* xp = x + (size_t)vb*(DIM*DIM*DIM);
  for(int p=threadIdx.x; p<DIM*DIM*DIM; p+=256) sh[p] = silu(xp[p]);
  __syncthreads();
  const int wave = threadIdx.x>>6, lane = threadIdx.x&63;
  for(int tap=wave; tap<27; tap+=4){
    const int kd=tap/9, kh=(tap/3)%3, kw=tap%3;
    const int base = kd*DIM*DIM + kh*DIM + kw;
    float ps = 0.f;
    for(int idx=lane; idx<ODIM*ODIM*ODIM; idx+=64){
      int od = idx/(ODIM*ODIM); int r = idx - od*(ODIM*ODIM);
      int oh = r/ODIM; int ow = r - oh*ODIM;
      ps += sh[base + od*DIM*DIM + oh*DIM + ow];
    }
    #pragma unroll
    for(int m=32;m>=1;m>>=1) ps += __shfl_xor(ps,m);
    if(lane==0) S[vb*27 + tap] = ps;
  }
}

__global__ __launch_bounds__(256,4) void k_mega(Params P){
  __shared__ float sh[4096];                    // 16 KB, aliased per phase
  const int b = blockIdx.x;
  const int tid = threadIdx.x;

  //=============== P0: preprocessing (3008 tasks over 1024 blocks) ===============
  for(int t = b; t < 3008; t += GRID){
    if(t < 512){
      // tok row t: silu -> sumsilu (atomic) ; fp16 tok_h
      const int row = t;
      float sv = silu(P.tf[row*256 + tid]);
      sh[tid] = sv;
      atomicAdd(&P.sumsilu[(row>>7)*256 + tid], sv);
      __syncthreads();
      const int c = tid & 127, sg = tid >> 7;
      float acc = 0.f;
      #pragma unroll 8
      for(int q=sg*128; q<sg*128+128; q++) acc = fmaf(sh[q], P.Wtok[q*128+c], acc);
      if(sg==1) sh[256+c] = acc;
      __syncthreads();
      if(sg==0){
        float v = acc + sh[256+c] + P.btok[c];
        P.tok_h[row*128+c] = __builtin_bit_cast(unsigned short, (_Float16)v);
      }
    } else if(t < 768){
      wsum_body<8,6>(P.ms1, P.S1, t-512, sh);
    } else if(t < 896){
      wsum_body<16,14>(P.ms0, P.S0, t-768, sh);
    } else if(t < 2944){
      // atoms (fp16): 2 rows per task ; zero atom_e
      const int rowb = (t-896)*2;
      if(tid < 128) sh[tid] = P.la[(size_t)rowb*64 + tid];
      __syncthreads();
      const int r2 = tid>>7, c = tid&127;
      const float* s = sh + r2*64;
      float acc = P.ba[c];
      #pragma unroll 8
      for(int k=0;k<64;k++) acc = fmaf(s[k], P.Wa[k*128+c], acc);
      P.atoms_h[(size_t)(rowb+r2)*128 + c] = __builtin_bit_cast(unsigned short, (_Float16)acc);
      if(tid<2) P.atom_e[rowb+tid] = 0.f;
    } else {
      // Wt[c][k] = fp16(Wint[k][c])
      const int idx = (t-2944)*256 + tid;
      const int c = idx >> 7, k = idx & 127;
      P.Wt[c*128 + k] = __builtin_bit_cast(unsigned short, (_Float16)(P.Wint[k*128 + c]));
    }
    __syncthreads();   // sh reused next task
  }

  gridbar(P.bar);

  //=============== P1: interaction GEMM (1024 tasks of 64 atoms x 8 j) ===============
  {
    const int bs = ((b & 7) << 7) + (b >> 3);   // XCD swizzle, bijective on [0,1024)
    const int n = bs >> 8;
    const int chunk = (bs >> 4) & 15;           // 16 chunks of 64 atoms
    const int jg = bs & 15;                     // j base = jg*8
    const int w = tid >> 6, lane = tid & 63;
    const int t16 = lane & 15, q = lane >> 4;
    const int g = w >> 1, wc = w & 1;
    float* red = sh;                            // [j][g][wc][row16][2] = 1024 f

    float bi[4], wpe[4], wpg[4];
    #pragma unroll
    for(int fc=0;fc<4;fc++){
      int cc = wc*64 + fc*16 + t16;
      bi[fc]=P.bint[cc]; wpe[fc]=P.Wpe[cc]; wpg[fc]=P.Wpg[cc];
    }
    const float bpe0 = P.bpe[0], bpg0 = P.bpg[0];
    const unsigned short* tokh = P.tok_h + (size_t)(n*128 + jg*8)*128 + q*8;

    for(int sub=0; sub<2; sub++){
      const int rbase = n*1024 + chunk*64 + sub*32;
      half8v areg[4];
      { const unsigned short* ab = P.atoms_h + (size_t)(rbase + g*16 + t16)*128 + q*8;
        #pragma unroll
        for(int ks=0;ks<4;ks++) areg[ks] = *(const half8v*)(ab + ks*32);
      }
      half8v breg[4][4];
      { const unsigned short* wb = P.Wt + (size_t)(wc*64 + t16)*128 + q*8;
        #pragma unroll
        for(int fc=0;fc<4;fc++)
          #pragma unroll
          for(int ks=0;ks<4;ks++)
            breg[fc][ks] = *(const half8v*)(wb + fc*16*128 + ks*32);
      }
      #pragma unroll 2
      for(int j=0;j<8;j++){
        half8v th[4];
        #pragma unroll
        for(int ks=0;ks<4;ks++) th[ks] = *(const half8v*)(tokh + j*128 + ks*32);
        float4v acc[4];
        #pragma unroll
        for(int fc=0;fc<4;fc++) acc[fc] = (float4v){bi[fc],bi[fc],bi[fc],bi[fc]};
        #pragma unroll
        for(int ks=0;ks<4;ks++){
          half8v s = areg[ks] * th[ks];         // v_pk_mul_f16 x4
          #pragma unroll
          for(int fc=0;fc<4;fc++)
            acc[fc] = __builtin_amdgcn_mfma_f32_16x16x32_f16(s, breg[fc][ks], acc[fc], 0,0,0);
        }
        #pragma unroll
        for(int r=0;r<4;r++){
          float d1=0.f, d2=0.f;
          #pragma unroll
          for(int fc=0;fc<4;fc++){
            float h = lrelu(acc[fc][r]);
            d1 = fmaf(h, wpe[fc], d1);
            d2 = fmaf(h, wpg[fc], d2);
          }
          d1 = row16_reduce(d1);
          d2 = row16_reduce(d2);
          if(t16==0){
            int rr = q*4+r;
            red[(((j*2+g)*2+wc)*16 + rr)*2 + 0] = d1;
            red[(((j*2+g)*2+wc)*16 + rr)*2 + 1] = d2;
          }
        }
      }
      __syncthreads();
      if(tid < 32){
        const int gg = tid >> 4, a = tid & 15;
        float s_ = 0.f;
        #pragma unroll
        for(int j=0;j<8;j++){
          float d1 = red[(((j*2+gg)*2+0)*16+a)*2+0] + red[(((j*2+gg)*2+1)*16+a)*2+0];
          float d2 = red[(((j*2+gg)*2+0)*16+a)*2+1] + red[(((j*2+gg)*2+1)*16+a)*2+1];
          s_ += (d1 + bpe0) * sigm(d2 + bpg0);
        }
        atomicAdd(P.atom_e + rbase + tid, s_);
      }
      __syncthreads();
    }
  }

  //----- pocket chain, blocks 1020-1023 (one per n), in P1's shadow -----
  if(b >= GRID-4){
    const int n = b - (GRID-4);
    float* pp_s = sh;          // 256
    float* ts_s = sh + 256;    // 128
    float* zz   = sh + 384;    // 384
    if(tid < 128){
      float ts = 128.f * P.btok[tid];
      for(int q2=0;q2<256;q2++) ts = fmaf(P.sumsilu[n*256+q2], P.Wtok[q2*128+tid], ts);
      ts_s[tid] = ts;
      const float* w = P.Wc0 + tid*1728; const float* s = P.S1 + n*1728;
      float a = 0.f;
      for(int q2=0;q2<1728;q2++) a = fmaf(w[q2], s[q2], a);
      pp_s[tid] = silu(P.bc0[tid] + a*(1.f/216.f));
    } else {
      const int c2 = tid-128;
      const float* w = P.Wc1 + c2*864; const float* s = P.S0 + n*864;
      float a = 0.f;
      for(int q2=0;q2<864;q2++) a = fmaf(w[q2], s[q2], a);
      pp_s[128+c2] = silu(P.bc1[c2] + a*(1.f/2744.f));
    }
    __syncthreads();
    if(tid < 128){
      float pk = P.bp[tid];
      for(int q2=0;q2<256;q2++) pk = fmaf(pp_s[q2], P.Wp[q2*128+tid], pk);
      zz[tid] = pk; zz[128+tid] = ts_s[tid]; zz[256+tid] = ts_s[tid]*(1.f/128.f);
    }
    __syncthreads();
    if(tid < 128){
      float a1 = P.bcat[tid], a2 = P.bgate[tid];
      for(int q2=0;q2<384;q2++){
        float z = zz[q2];
        a1 = fmaf(z, P.Wcat[q2*128+tid], a1);
        a2 = fmaf(z, P.Wgate[q2*128+tid], a2);
      }
      P.pf[n*128+tid] = a1 * sigm(a2);
    }
  }

  gridbar(P.bar);

  //=============== P2: bias head + segment-sum (blocks 0-255 as (n,g)) ===============
  if(b < 256){
    const int n = b >> 6, g2 = b & 63;
    float* row = sh;         // 64
    float* z   = sh + 64;    // 256
    float* pA  = sh + 320;   // 128
    float* pB  = sh + 448;   // 128
    float* wr  = sh + 576;   // 4
    const int c = tid & 127, s = tid >> 7;
    if(tid < 64) row[tid] = P.lg[(size_t)(n*64+g2)*64 + tid];
    __syncthreads();
    float gf = 0.f;
    #pragma unroll 8
    for(int k=s*32;k<s*32+32;k++) gf = fmaf(row[k], P.Wg[k*128+c], gf);
    if(s==1) pA[c] = gf;
    __syncthreads();
    if(s==0){ z[c] = P.pf[n*128+c]; z[128+c] = gf + pA[c] + P.bg[c]; }
    __syncthreads();
    float tacc = 0.f;
    for(int qq=s*128; qq<s*128+128; qq++) tacc = fmaf(z[qq], P.W1[qq*128+c], tacc);
    if(s==1) pB[c] = tacc;
    float se = 0.f;
    const float* ae = P.atom_e + n*1024;
    for(int i=tid;i<1024;i+=256){ float v = ae[i]; se += (P.batch[i]==g2) ? v : 0.f; }
    __syncthreads();
    float val = se;
    if(s==0) val += lrelu(tacc + pB[c] + P.b1[c]) * P.W2[c];
    #pragma unroll
    for(int m=32;m>=1;m>>=1) val += __shfl_xor(val,m);
    if((tid&63)==0) wr[tid>>6] = val;
    __syncthreads();
    if(tid==0) P.out[n*64+g2] = wr[0]+wr[1]+wr[2]+wr[3] + P.b2[0];
  }
}

extern "C" void kernel_launch(void* const* d_in, const int* in_sizes, int n_in,
                              void* d_out, int out_size, void* d_ws, size_t ws_size,
                              hipStream_t stream) {
  Params P;
  P.tf    = (const float*)d_in[2];
  P.ms1   = (const float*)d_in[1];
  P.ms0   = (const float*)d_in[0];
  P.la    = (const float*)d_in[3];
  P.lg    = (const float*)d_in[4];
  P.batch = (const int*)  d_in[5];
  P.Wtok  = (const float*)d_in[6];
  P.btok  = (const float*)d_in[7];
  P.Wc0   = (const float*)d_in[8];
  P.bc0   = (const float*)d_in[9];
  P.Wc1   = (const float*)d_in[10];
  P.bc1   = (const float*)d_in[11];
  P.Wp    = (const float*)d_in[12];
  P.bp    = (const float*)d_in[13];
  P.Wcat  = (const float*)d_in[14];
  P.bcat  = (const float*)d_in[15];
  P.Wgate = (const float*)d_in[16];
  P.bgate = (const float*)d_in[17];
  P.Wa    = (const float*)d_in[18];
  P.ba    = (const float*)d_in[19];
  P.Wg    = (const float*)d_in[20];
  P.bg    = (const float*)d_in[21];
  P.W1    = (const float*)d_in[22];
  P.b1    = (const float*)d_in[23];
  P.W2    = (const float*)d_in[24];
  P.b2    = (const float*)d_in[25];
  P.Wint  = (const float*)d_in[26];
  P.bint  = (const float*)d_in[27];
  P.Wpe   = (const float*)d_in[28];
  P.bpe   = (const float*)d_in[29];
  P.Wpg   = (const float*)d_in[30];
  P.bpg   = (const float*)d_in[31];
  P.out   = (float*)d_out;

  float* ws = (float*)d_ws;
  P.bar     = (int*)ws;                        // 8 floats reserved (2 used)
  P.sumsilu = ws + 8;                          // 1024
  P.S1      = ws + 8 + 1024;                   // 6912
  P.S0      = P.S1 + 6912;                     // 3456
  P.atom_e  = P.S0 + 3456;                     // 4096
  P.pf      = P.atom_e + 4096;                 // 512
  P.atoms_h = (unsigned short*)(P.pf + 512);   // 524288 u16 (16B-aligned: 16008 f)
  P.Wt      = P.atoms_h + 524288;              // 16384 u16
  P.tok_h   = P.Wt + 16384;                    // 65536 u16

  // barrier state + sumsilu must start at 0 (ws is poisoned 0xAA each call)
  hipMemsetAsync(ws, 0, (8 + 1024)*sizeof(float), stream);

  k_mega<<<GRID, 256, 0, stream>>>(P);
}

// Round 12
// 1003.000 us; speedup vs baseline: 1.9821x; 1.9821x over previous
//
#include <hip/hip_runtime.h>
#include <hip/hip_bf16.h>

#define NIMG 4
#define GRID 512

typedef __attribute__((ext_vector_type(8))) _Float16 half8v;
typedef __attribute__((ext_vector_type(4))) float float4v;

__device__ __forceinline__ float sigm(float x){ return 1.f/(1.f+__expf(-x)); }
__device__ __forceinline__ float silu(float x){ return x/(1.f+__expf(-x)); }
__device__ __forceinline__ float lrelu(float x){ return fmaxf(x, 0.01f*x); }

template<int CTRL>
__device__ __forceinline__ float dpp_radd(float v){
  int s = __builtin_amdgcn_update_dpp(0, __builtin_bit_cast(int, v), CTRL, 0xF, 0xF, true);
  return v + __builtin_bit_cast(float, s);
}
__device__ __forceinline__ float row16_reduce(float v){
  v = dpp_radd<0x128>(v);  // row_ror:8
  v = dpp_radd<0x124>(v);  // row_ror:4
  v = dpp_radd<0x122>(v);  // row_ror:2
  v = dpp_radd<0x121>(v);  // row_ror:1
  return v;
}

struct Params {
  const float *tf, *Wtok, *btok;
  const float *ms1, *ms0;
  const float *la, *Wa, *ba;
  const float *Wint;
  const float *Wc0, *bc0, *Wc1, *bc1;
  const float *Wp, *bp, *Wcat, *bcat, *Wgate, *bgate;
  const float *lg, *Wg, *bg, *W1, *b1, *W2, *b2;
  const float *bint, *Wpe, *bpe, *Wpg, *bpg;
  const int *batch;
  int *bar;
  float *sumsilu, *S1, *S0, *atom_e, *pf, *out;
  unsigned short *atoms_h, *Wt, *tok_h;
};

// generational grid barrier; all GRID blocks must be co-resident.
__device__ __forceinline__ void gridbar(int* bar){
  __threadfence();                 // release my writes (agent scope)
  __syncthreads();
  if(threadIdx.x==0){
    int g = __hip_atomic_load(&bar[1], __ATOMIC_RELAXED, __HIP_MEMORY_SCOPE_AGENT);
    int old = __hip_atomic_fetch_add(&bar[0], 1, __ATOMIC_ACQ_REL, __HIP_MEMORY_SCOPE_AGENT);
    if(old == GRID-1){
      __hip_atomic_store(&bar[0], 0, __ATOMIC_RELAXED, __HIP_MEMORY_SCOPE_AGENT);
      __hip_atomic_fetch_add(&bar[1], 1, __ATOMIC_RELEASE, __HIP_MEMORY_SCOPE_AGENT);
    } else {
      while(__hip_atomic_load(&bar[1], __ATOMIC_ACQUIRE, __HIP_MEMORY_SCOPE_AGENT) == g)
        __builtin_amdgcn_s_sleep(8);
    }
  }
  __syncthreads();
  __threadfence();                 // acquire: see others' writes
}

template<int DIM, int ODIM>
__device__ void wsum_body(const float* __restrict__ x, float* __restrict__ S,
                          int vb, float* sh){
  const float* xp = x + (size_t)vb*(DIM*DIM*DIM);
  for(int p=threadIdx.x; p<DIM*DIM*DIM; p+=256) sh[p] = silu(xp[p]);
  __syncthreads();
  const int wave = threadIdx.x>>6, lane = threadIdx.x&63;
  for(int tap=wave; tap<27; tap+=4){
    const int kd=tap/9, kh=(tap/3)%3, kw=tap%3;
    const int base = kd*DIM*DIM + kh*DIM + kw;
    float ps = 0.f;
    for(int idx=lane; idx<ODIM*ODIM*ODIM; idx+=64){
      int od = idx/(ODIM*ODIM); int r = idx - od*(ODIM*ODIM);
      int oh = r/ODIM; int ow = r - oh*ODIM;
      ps += sh[base + od*DIM*DIM + oh*DIM + ow];
    }
    #pragma unroll
    for(int m=32;m>=1;m>>=1) ps += __shfl_xor(ps,m);
    if(lane==0) S[vb*27 + tap] = ps;
  }
}

__global__ __launch_bounds__(256,2) void k_mega(Params P){
  __shared__ float sh[4096];                    // 16 KB, aliased per phase
  const int b = blockIdx.x;
  const int tid = threadIdx.x;

  //=============== P0: preprocessing (3008 tasks over 512 blocks) ===============
  for(int t = b; t < 3008; t += GRID){
    if(t < 512){
      // tok row t: silu -> sumsilu (atomic) ; fp16 tok_h
      const int row = t;
      float sv = silu(P.tf[row*256 + tid]);
      sh[tid] = sv;
      atomicAdd(&P.sumsilu[(row>>7)*256 + tid], sv);
      __syncthreads();
      const int c = tid & 127, sg = tid >> 7;
      float acc = 0.f;
      #pragma unroll 8
      for(int q=sg*128; q<sg*128+128; q++) acc = fmaf(sh[q], P.Wtok[q*128+c], acc);
      if(sg==1) sh[256+c] = acc;
      __syncthreads();
      if(sg==0){
        float v = acc + sh[256+c] + P.btok[c];
        P.tok_h[row*128+c] = __builtin_bit_cast(unsigned short, (_Float16)v);
      }
    } else if(t < 768){
      wsum_body<8,6>(P.ms1, P.S1, t-512, sh);
    } else if(t < 896){
      wsum_body<16,14>(P.ms0, P.S0, t-768, sh);
    } else if(t < 2944){
      // atoms (fp16): 2 rows per task ; zero atom_e
      const int rowb = (t-896)*2;
      if(tid < 128) sh[tid] = P.la[(size_t)rowb*64 + tid];
      __syncthreads();
      const int r2 = tid>>7, c = tid&127;
      const float* s = sh + r2*64;
      float acc = P.ba[c];
      #pragma unroll 8
      for(int k=0;k<64;k++) acc = fmaf(s[k], P.Wa[k*128+c], acc);
      P.atoms_h[(size_t)(rowb+r2)*128 + c] = __builtin_bit_cast(unsigned short, (_Float16)acc);
      if(tid<2) P.atom_e[rowb+tid] = 0.f;
    } else {
      // Wt[c][k] = fp16(Wint[k][c])
      const int idx = (t-2944)*256 + tid;
      const int c = idx >> 7, k = idx & 127;
      P.Wt[c*128 + k] = __builtin_bit_cast(unsigned short, (_Float16)(P.Wint[k*128 + c]));
    }
    __syncthreads();   // sh reused next task
  }

  gridbar(P.bar);

  //=============== P1: interaction GEMM (2048 tasks of 32 atoms x 8 j) ===============
  {
    const int w = tid >> 6, lane = tid & 63;
    const int t16 = lane & 15, q = lane >> 4;
    const int g = w >> 1, wc = w & 1;
    float* red = sh;                            // [j][g][wc][row16][2] = 1024 f

    // task-invariant: B fragments (W^T fp16) + epilogue constants
    half8v breg[4][4];
    { const unsigned short* wb = P.Wt + (size_t)(wc*64 + t16)*128 + q*8;
      #pragma unroll
      for(int fc=0;fc<4;fc++)
        #pragma unroll
        for(int ks=0;ks<4;ks++)
          breg[fc][ks] = *(const half8v*)(wb + fc*16*128 + ks*32);
    }
    float bi[4], wpe[4], wpg[4];
    #pragma unroll
    for(int fc=0;fc<4;fc++){
      int cc = wc*64 + fc*16 + t16;
      bi[fc]=P.bint[cc]; wpe[fc]=P.Wpe[cc]; wpg[fc]=P.Wpg[cc];
    }
    const float bpe0 = P.bpe[0], bpg0 = P.bpg[0];

    const int bs = ((b & 7) << 6) + (b >> 3);   // XCD swizzle, bijective on [0,512)
    for(int t = bs; t < 2048; t += GRID){
      const int n = t >> 9;
      const int chunk = (t >> 4) & 31;          // 32 chunks of 32 atoms
      const int jg = t & 15;                    // j base = jg*8
      const int rbase = n*1024 + chunk*32;
      const unsigned short* tokh = P.tok_h + (size_t)(n*128 + jg*8)*128 + q*8;

      half8v areg[4];
      { const unsigned short* ab = P.atoms_h + (size_t)(rbase + g*16 + t16)*128 + q*8;
        #pragma unroll
        for(int ks=0;ks<4;ks++) areg[ks] = *(const half8v*)(ab + ks*32);
      }
      #pragma unroll 2
      for(int j=0;j<8;j++){
        half8v th[4];
        #pragma unroll
        for(int ks=0;ks<4;ks++) th[ks] = *(const half8v*)(tokh + j*128 + ks*32);
        float4v acc[4];
        #pragma unroll
        for(int fc=0;fc<4;fc++) acc[fc] = (float4v){bi[fc],bi[fc],bi[fc],bi[fc]};
        #pragma unroll
        for(int ks=0;ks<4;ks++){
          half8v s = areg[ks] * th[ks];         // v_pk_mul_f16 x4
          #pragma unroll
          for(int fc=0;fc<4;fc++)
            acc[fc] = __builtin_amdgcn_mfma_f32_16x16x32_f16(s, breg[fc][ks], acc[fc], 0,0,0);
        }
        #pragma unroll
        for(int r=0;r<4;r++){
          float d1=0.f, d2=0.f;
          #pragma unroll
          for(int fc=0;fc<4;fc++){
            float h = lrelu(acc[fc][r]);
            d1 = fmaf(h, wpe[fc], d1);
            d2 = fmaf(h, wpg[fc], d2);
          }
          d1 = row16_reduce(d1);
          d2 = row16_reduce(d2);
          if(t16==0){
            int rr = q*4+r;
            red[(((j*2+g)*2+wc)*16 + rr)*2 + 0] = d1;
            red[(((j*2+g)*2+wc)*16 + rr)*2 + 1] = d2;
          }
        }
      }
      __syncthreads();
      if(tid < 32){
        const int gg = tid >> 4, a = tid & 15;
        float s_ = 0.f;
        #pragma unroll
        for(int j=0;j<8;j++){
          float d1 = red[(((j*2+gg)*2+0)*16+a)*2+0] + red[(((j*2+gg)*2+1)*16+a)*2+0];
          float d2 = red[(((j*2+gg)*2+0)*16+a)*2+1] + red[(((j*2+gg)*2+1)*16+a)*2+1];
          s_ += (d1 + bpe0) * sigm(d2 + bpg0);
        }
        atomicAdd(P.atom_e + rbase + tid, s_);
      }
      __syncthreads();
    }
  }

  //----- pocket chain, blocks 508-511 (one per n), in P1's shadow -----
  if(b >= GRID-4){
    const int n = b - (GRID-4);
    float* pp_s = sh;          // 256
    float* ts_s = sh + 256;    // 128
    float* zz   = sh + 384;    // 384
    __syncthreads();
    if(tid < 128){
      float ts = 128.f * P.btok[tid];
      for(int q2=0;q2<256;q2++) ts = fmaf(P.sumsilu[n*256+q2], P.Wtok[q2*128+tid], ts);
      ts_s[tid] = ts;
      const float* w = P.Wc0 + tid*1728; const float* s = P.S1 + n*1728;
      float a = 0.f;
      for(int q2=0;q2<1728;q2++) a = fmaf(w[q2], s[q2], a);
      pp_s[tid] = silu(P.bc0[tid] + a*(1.f/216.f));
    } else {
      const int c2 = tid-128;
      const float* w = P.Wc1 + c2*864; const float* s = P.S0 + n*864;
      float a = 0.f;
      for(int q2=0;q2<864;q2++) a = fmaf(w[q2], s[q2], a);
      pp_s[128+c2] = silu(P.bc1[c2] + a*(1.f/2744.f));
    }
    __syncthreads();
    if(tid < 128){
      float pk = P.bp[tid];
      for(int q2=0;q2<256;q2++) pk = fmaf(pp_s[q2], P.Wp[q2*128+tid], pk);
      zz[tid] = pk; zz[128+tid] = ts_s[tid]; zz[256+tid] = ts_s[tid]*(1.f/128.f);
    }
    __syncthreads();
    if(tid < 128){
      float a1 = P.bcat[tid], a2 = P.bgate[tid];
      for(int q2=0;q2<384;q2++){
        float z = zz[q2];
        a1 = fmaf(z, P.Wcat[q2*128+tid], a1);
        a2 = fmaf(z, P.Wgate[q2*128+tid], a2);
      }
      P.pf[n*128+tid] = a1 * sigm(a2);
    }
  }

  gridbar(P.bar);

  //=============== P2: bias head + segment-sum (blocks 0-255 as (n,g)) ===============
  if(b < 256){
    const int n = b >> 6, g2 = b & 63;
    float* row = sh;         // 64
    float* z   = sh + 64;    // 256
    float* pA  = sh + 320;   // 128
    float* pB  = sh + 448;   // 128
    float* wr  = sh + 576;   // 4
    const int c = tid & 127, s = tid >> 7;
    if(tid < 64) row[tid] = P.lg[(size_t)(n*64+g2)*64 + tid];
    __syncthreads();
    float gf = 0.f;
    #pragma unroll 8
    for(int k=s*32;k<s*32+32;k++) gf = fmaf(row[k], P.Wg[k*128+c], gf);
    if(s==1) pA[c] = gf;
    __syncthreads();
    if(s==0){ z[c] = P.pf[n*128+c]; z[128+c] = gf + pA[c] + P.bg[c]; }
    __syncthreads();
    float tacc = 0.f;
    for(int qq=s*128; qq<s*128+128; qq++) tacc = fmaf(z[qq], P.W1[qq*128+c], tacc);
    if(s==1) pB[c] = tacc;
    float se = 0.f;
    const float* ae = P.atom_e + n*1024;
    for(int i=tid;i<1024;i+=256){ float v = ae[i]; se += (P.batch[i]==g2) ? v : 0.f; }
    __syncthreads();
    float val = se;
    if(s==0) val += lrelu(tacc + pB[c] + P.b1[c]) * P.W2[c];
    #pragma unroll
    for(int m=32;m>=1;m>>=1) val += __shfl_xor(val,m);
    if((tid&63)==0) wr[tid>>6] = val;
    __syncthreads();
    if(tid==0) P.out[n*64+g2] = wr[0]+wr[1]+wr[2]+wr[3] + P.b2[0];
  }
}

extern "C" void kernel_launch(void* const* d_in, const int* in_sizes, int n_in,
                              void* d_out, int out_size, void* d_ws, size_t ws_size,
                              hipStream_t stream) {
  Params P;
  P.tf    = (const float*)d_in[2];
  P.ms1   = (const float*)d_in[1];
  P.ms0   = (const float*)d_in[0];
  P.la    = (const float*)d_in[3];
  P.lg    = (const float*)d_in[4];
  P.batch = (const int*)  d_in[5];
  P.Wtok  = (const float*)d_in[6];
  P.btok  = (const float*)d_in[7];
  P.Wc0   = (const float*)d_in[8];
  P.bc0   = (const float*)d_in[9];
  P.Wc1   = (const float*)d_in[10];
  P.bc1   = (const float*)d_in[11];
  P.Wp    = (const float*)d_in[12];
  P.bp    = (const float*)d_in[13];
  P.Wcat  = (const float*)d_in[14];
  P.bcat  = (const float*)d_in[15];
  P.Wgate = (const float*)d_in[16];
  P.bgate = (const float*)d_in[17];
  P.Wa    = (const float*)d_in[18];
  P.ba    = (const float*)d_in[19];
  P.Wg    = (const float*)d_in[20];
  P.bg    = (const float*)d_in[21];
  P.W1    = (const float*)d_in[22];
  P.b1    = (const float*)d_in[23];
  P.W2    = (const float*)d_in[24];
  P.b2    = (const float*)d_in[25];
  P.Wint  = (const float*)d_in[26];
  P.bint  = (const float*)d_in[27];
  P.Wpe   = (const float*)d_in[28];
  P.bpe   = (const float*)d_in[29];
  P.Wpg   = (const float*)d_in[30];
  P.bpg   = (const float*)d_in[31];
  P.out   = (float*)d_out;

  float* ws = (float*)d_ws;
  P.bar     = (int*)ws;                        // 8 floats reserved (2 used)
  P.sumsilu = ws + 8;                          // 1024
  P.S1      = ws + 8 + 1024;                   // 6912
  P.S0      = P.S1 + 6912;                     // 3456
  P.atom_e  = P.S0 + 3456;                     // 4096
  P.pf      = P.atom_e + 4096;                 // 512
  P.atoms_h = (unsigned short*)(P.pf + 512);   // 524288 u16 (16B-aligned: 16008 f)
  P.Wt      = P.atoms_h + 524288;              // 16384 u16
  P.tok_h   = P.Wt + 16384;                    // 65536 u16

  // barrier state + sumsilu must start at 0 (ws is poisoned 0xAA each call)
  hipMemsetAsync(ws, 0, (8 + 1024)*sizeof(float), stream);

  k_mega<<<GRID, 256, 0, stream>>>(P);
}